// Round 1
// baseline (1501.656 us; speedup 1.0000x reference)
//
#include <hip/hip_runtime.h>
#include <math.h>

#define T_SEQ 2048
#define C_DIM 1024
#define NHEAD 16
#define HDIM 64
#define M_ROWS 4096   // B*T
#define N_QKV 3072    // 3*C

// ---------------- abs-mean scale (deterministic 2-stage reduction) ----------
__global__ __launch_bounds__(256) void abs_partial_k(const float* __restrict__ w,
                                                     int n, float* __restrict__ part) {
  __shared__ float red[256];
  float s = 0.f;
  for (int i = blockIdx.x * 256 + threadIdx.x; i < n; i += 256 * 256)
    s += fabsf(w[i]);
  red[threadIdx.x] = s;
  __syncthreads();
  for (int st = 128; st > 0; st >>= 1) {
    if ((int)threadIdx.x < st) red[threadIdx.x] += red[threadIdx.x + st];
    __syncthreads();
  }
  if (threadIdx.x == 0) part[blockIdx.x] = red[0];
}

__global__ __launch_bounds__(256) void finalize_scales_k(const float* __restrict__ part,
                                                         float* __restrict__ scales) {
  __shared__ float red[256];
  red[threadIdx.x] = part[blockIdx.x * 256 + threadIdx.x];
  __syncthreads();
  for (int st = 128; st > 0; st >>= 1) {
    if ((int)threadIdx.x < st) red[threadIdx.x] += red[threadIdx.x + st];
    __syncthreads();
  }
  if (threadIdx.x == 0) {
    float n = (blockIdx.x == 0) ? (float)(N_QKV * C_DIM) : (float)(C_DIM * C_DIM);
    scales[blockIdx.x] = fmaxf(red[0] / n, 1e-8f);
  }
}

// ---------------- ternarize: clip(round(w/scale), -1, 1) --------------------
__global__ __launch_bounds__(256) void ternarize_k(const float* __restrict__ w,
                                                   float* __restrict__ wt, int n,
                                                   const float* __restrict__ scales,
                                                   int which) {
  int i = blockIdx.x * 256 + threadIdx.x;
  if (i < n) {
    float s = scales[which];
    float t = rintf(w[i] / s);           // rintf = round-half-even, matches jnp.round
    wt[i] = fminf(1.f, fmaxf(-1.f, t));
  }
}

// ---------------- fp32 GEMM: C[m][n] = sum_k A[m][k] * Bw[n][k] -------------
// 64x64 tile, BK=16, 256 threads, 4x4 micro-tile per thread.
__global__ __launch_bounds__(256, 2) void gemm_nt(const float* __restrict__ A,
                                                  const float* __restrict__ Bw,
                                                  float* __restrict__ Cout,
                                                  int Nd, int Kd) {
  __shared__ __align__(16) float As[16][64];
  __shared__ __align__(16) float Bs[16][64];
  const int bm = blockIdx.y * 64;
  const int bn = blockIdx.x * 64;
  const int tid = threadIdx.x;
  const int tm = tid >> 4, tn = tid & 15;
  const int lr = tid >> 2;
  const int lk = (tid & 3) << 2;
  const float* Ap = A + (size_t)(bm + lr) * Kd + lk;
  const float* Bp = Bw + (size_t)(bn + lr) * Kd + lk;
  float acc[4][4] = {};
  for (int k0 = 0; k0 < Kd; k0 += 16) {
    const float4 av = *(const float4*)(Ap + k0);
    const float4 bv = *(const float4*)(Bp + k0);
    __syncthreads();
    As[lk + 0][lr] = av.x; As[lk + 1][lr] = av.y;
    As[lk + 2][lr] = av.z; As[lk + 3][lr] = av.w;
    Bs[lk + 0][lr] = bv.x; Bs[lk + 1][lr] = bv.y;
    Bs[lk + 2][lr] = bv.z; Bs[lk + 3][lr] = bv.w;
    __syncthreads();
#pragma unroll
    for (int k = 0; k < 16; ++k) {
      const float4 a = *(const float4*)(&As[k][tm << 2]);
      const float4 b = *(const float4*)(&Bs[k][tn << 2]);
      float a4[4] = {a.x, a.y, a.z, a.w};
      float b4[4] = {b.x, b.y, b.z, b.w};
#pragma unroll
      for (int i = 0; i < 4; ++i)
#pragma unroll
        for (int j = 0; j < 4; ++j)
          acc[i][j] = fmaf(a4[i], b4[j], acc[i][j]);
    }
  }
#pragma unroll
  for (int i = 0; i < 4; ++i) {
    float4 o = make_float4(acc[i][0], acc[i][1], acc[i][2], acc[i][3]);
    *(float4*)(Cout + (size_t)(bm + (tm << 2) + i) * Nd + bn + (tn << 2)) = o;
  }
}

// ---------------- flash-style causal attention, fp32 ------------------------
// One query row per thread; 256 queries per block; K/V chunks of 128 in LDS.
__global__ __launch_bounds__(256, 2) void attn_k(const float* __restrict__ qkv,
                                                 float* __restrict__ aout) {
  const int tid = threadIdx.x;
  const int qt = blockIdx.x & 7;          // T/256 = 8 query tiles
  const int h  = (blockIdx.x >> 3) & 15;
  const int b  = blockIdx.x >> 7;
  const int qi = (qt << 8) + tid;
  const float* base = qkv + (size_t)b * T_SEQ * N_QKV;
  const float* qrow = base + (size_t)qi * N_QKV + (h << 6);

  float q[64], acc[64];
#pragma unroll
  for (int i = 0; i < 16; ++i) {
    float4 v4 = *(const float4*)(qrow + (i << 2));
    q[i * 4 + 0] = v4.x * 0.125f;   // fold 1/sqrt(64) into q
    q[i * 4 + 1] = v4.y * 0.125f;
    q[i * 4 + 2] = v4.z * 0.125f;
    q[i * 4 + 3] = v4.w * 0.125f;
  }
#pragma unroll
  for (int d = 0; d < 64; ++d) acc[d] = 0.f;
  float mrow = -INFINITY, lrow = 0.f;

  __shared__ __align__(16) float ks[128][64];
  __shared__ __align__(16) float vs[128][64];

  const int kend = (qt << 8) + 256;       // no key beyond this block's max query
  for (int k0 = 0; k0 < kend; k0 += 128) {
    __syncthreads();
#pragma unroll
    for (int i = 0; i < 8; ++i) {
      int idx = (i << 8) + tid;           // 0..2047 float4 slots
      int kr = idx >> 4, d4 = (idx & 15) << 2;
      const float* kp = base + (size_t)(k0 + kr) * N_QKV + C_DIM + (h << 6) + d4;
      *(float4*)(&ks[kr][d4]) = *(const float4*)(kp);
      *(float4*)(&vs[kr][d4]) = *(const float4*)(kp + C_DIM);
    }
    __syncthreads();

    const int klim = min(128, qi - k0 + 1);  // #valid keys for this thread
    for (int kk = 0; kk < klim; kk += 8) {
      float s[8];
#pragma unroll
      for (int j = 0; j < 8; ++j) {
        float dot = 0.f;
#pragma unroll
        for (int d4 = 0; d4 < 16; ++d4) {
          const float4 kv = *(const float4*)(&ks[kk + j][d4 << 2]);
          dot = fmaf(q[d4 * 4 + 0], kv.x, dot);
          dot = fmaf(q[d4 * 4 + 1], kv.y, dot);
          dot = fmaf(q[d4 * 4 + 2], kv.z, dot);
          dot = fmaf(q[d4 * 4 + 3], kv.w, dot);
        }
        s[j] = (kk + j < klim) ? dot : -INFINITY;
      }
      float mc = s[0];
#pragma unroll
      for (int j = 1; j < 8; ++j) mc = fmaxf(mc, s[j]);
      if (mc > mrow) {
        const float r = __expf(mrow - mc);  // exp(-inf)=0 handles first chunk
        lrow *= r;
#pragma unroll
        for (int d = 0; d < 64; ++d) acc[d] *= r;
        mrow = mc;
      }
#pragma unroll
      for (int j = 0; j < 8; ++j) {
        const float p = __expf(s[j] - mrow);
        lrow += p;
#pragma unroll
        for (int d4 = 0; d4 < 16; ++d4) {
          const float4 vv = *(const float4*)(&vs[kk + j][d4 << 2]);
          acc[d4 * 4 + 0] = fmaf(p, vv.x, acc[d4 * 4 + 0]);
          acc[d4 * 4 + 1] = fmaf(p, vv.y, acc[d4 * 4 + 1]);
          acc[d4 * 4 + 2] = fmaf(p, vv.z, acc[d4 * 4 + 2]);
          acc[d4 * 4 + 3] = fmaf(p, vv.w, acc[d4 * 4 + 3]);
        }
      }
    }
  }
  const float inv = 1.f / lrow;           // lrow >= 1 (diagonal key always valid)
  float* op = aout + (size_t)(b * T_SEQ + qi) * C_DIM + (h << 6);
#pragma unroll
  for (int i = 0; i < 16; ++i) {
    float4 o = make_float4(acc[i * 4 + 0] * inv, acc[i * 4 + 1] * inv,
                           acc[i * 4 + 2] * inv, acc[i * 4 + 3] * inv);
    *(float4*)(op + (i << 2)) = o;
  }
}

// ---------------- launch ----------------------------------------------------
extern "C" void kernel_launch(void* const* d_in, const int* in_sizes, int n_in,
                              void* d_out, int out_size, void* d_ws, size_t ws_size,
                              hipStream_t stream) {
  const float* x      = (const float*)d_in[0];   // [B,T,C] = [4096][1024]
  const float* w_qkv  = (const float*)d_in[1];   // [3072][1024]
  const float* w_out  = (const float*)d_in[2];   // [1024][1024]
  float* out = (float*)d_out;                    // [4096][1024]
  float* ws = (float*)d_ws;

  float* wt_qkv = ws;                                    // 3,145,728
  float* wt_out = wt_qkv + (size_t)N_QKV * C_DIM;        // 1,048,576
  float* qkv    = wt_out + (size_t)C_DIM * C_DIM;        // 12,582,912
  float* aout   = qkv + (size_t)M_ROWS * N_QKV;          // 4,194,304
  float* part   = aout + (size_t)M_ROWS * C_DIM;         // 512
  float* scales = part + 512;                            // 2

  // 1. abs-mean scales (deterministic)
  hipLaunchKernelGGL(abs_partial_k, dim3(256), dim3(256), 0, stream,
                     w_qkv, N_QKV * C_DIM, part);
  hipLaunchKernelGGL(abs_partial_k, dim3(256), dim3(256), 0, stream,
                     w_out, C_DIM * C_DIM, part + 256);
  hipLaunchKernelGGL(finalize_scales_k, dim3(2), dim3(256), 0, stream, part, scales);

  // 2. ternarize weights
  hipLaunchKernelGGL(ternarize_k, dim3((N_QKV * C_DIM) / 256), dim3(256), 0, stream,
                     w_qkv, wt_qkv, N_QKV * C_DIM, scales, 0);
  hipLaunchKernelGGL(ternarize_k, dim3((C_DIM * C_DIM) / 256), dim3(256), 0, stream,
                     w_out, wt_out, C_DIM * C_DIM, scales, 1);

  // 3. qkv = x @ wt_qkv^T   [4096 x 3072]
  hipLaunchKernelGGL(gemm_nt, dim3(N_QKV / 64, M_ROWS / 64), dim3(256), 0, stream,
                     x, wt_qkv, qkv, N_QKV, C_DIM);

  // 4. causal attention -> aout [4096 x 1024]
  hipLaunchKernelGGL(attn_k, dim3(256), dim3(256), 0, stream, qkv, aout);

  // 5. out = aout @ wt_out^T  [4096 x 1024]
  hipLaunchKernelGGL(gemm_nt, dim3(C_DIM / 64, M_ROWS / 64), dim3(256), 0, stream,
                     aout, wt_out, out, C_DIM, C_DIM);
}